// Round 7
// baseline (61.126 us; speedup 1.0000x reference)
//
#include <hip/hip_runtime.h>

// 256 independent MLPs (2->32->2), 16384 rows. VALU-bound.
// Round 7: R6 structure (lane=channel, per-lane VGPR weights from repacked ws,
// x rows in SGPR, direct coalesced stores) with the spill fixed: h-loop kept
// rolled (unroll 2), launch_bounds(64,4) -> 128 VGPR cap. R6's FETCH_SIZE of
// 702MB was scratch spill/fill traffic from full h-unroll under a 32-VGPR alloc.

#define NCH   256
#define HID   32
#define BATCH 16384
#define TPB   64    // one wave; lane = channel within group
#define ROWS  16    // batch rows per thread = 16 independent chains

// d_ws layout (floats): W0p[HID][NCH][2] | b0p[HID][NCH] | W1p[HID][NCH][2]
#define W0P_OFF 0
#define B0P_OFF (HID * NCH * 2)
#define W1P_OFF (B0P_OFF + HID * NCH)

__global__ __launch_bounds__(256) void repack_kernel(
    const float* __restrict__ W0,   // [NCH][HID][2]
    const float* __restrict__ b0,   // [NCH][HID]
    const float* __restrict__ W1,   // [NCH][2][HID]
    float* __restrict__ ws)
{
    int t = blockIdx.x * blockDim.x + threadIdx.x;   // 16384 threads
    {   // W0p[(h*NCH + c)*2 + i] = W0[c*64 + h*2 + i]
        int i = t & 1, c = (t >> 1) & 255, h = t >> 9;
        ws[W0P_OFF + t] = W0[c * (HID * 2) + h * 2 + i];
    }
    if (t < HID * NCH) {   // b0p[h*NCH + c] = b0[c*32 + h]
        int c = t & 255, h = t >> 8;
        ws[B0P_OFF + t] = b0[c * HID + h];
    }
    {   // W1p[(h*NCH + c)*2 + o] = W1[c*64 + o*32 + h]
        int o = t & 1, c = (t >> 1) & 255, h = t >> 9;
        ws[W1P_OFF + t] = W1[c * (2 * HID) + o * HID + h];
    }
}

static __device__ __forceinline__ float rfl(float v) {
    return __uint_as_float(__builtin_amdgcn_readfirstlane(__float_as_uint(v)));
}

__global__ __launch_bounds__(TPB, 4) void mlp_main(
    const float* __restrict__ x,    // [BATCH][2]
    const float* __restrict__ ws,   // repacked weights
    const float* __restrict__ b1,   // [NCH][2]
    float* __restrict__ out)        // [BATCH][NCH][2]
{
    // A&S 7.1.27 erf poly, sqrt(2) folded (|eps|<=5e-4); q = 2*gelu.
    const float A1 = 0.19685390f;
    const float A2 = 0.11519450f;
    const float A3 = 3.4365516e-4f;
    const float A4 = 0.019527f;

    const float2* __restrict__ W0p = (const float2*)(ws + W0P_OFF);  // [h*NCH+c] -> (wa,wb)
    const float*  __restrict__ b0p = ws + B0P_OFF;                   // [h*NCH+c]
    const float2* __restrict__ W1p = (const float2*)(ws + W1P_OFF);  // [h*NCH+c] -> (w1a,w1b)

    const int lane  = threadIdx.x;
    const int cb    = blockIdx.x & 3;        // channel group (4)
    const int rb    = blockIdx.x >> 2;       // row block (1024)
    const int c     = cb * 64 + lane;
    const int rbase = rb * ROWS;

    // x rows -> SGPRs (wave-uniform)
    float sx0[ROWS], sx1[ROWS];
    const float2* __restrict__ x2 = (const float2*)x;
    #pragma unroll
    for (int r = 0; r < ROWS; ++r) {
        float2 xr = x2[rbase + r];
        sx0[r] = rfl(xr.x);
        sx1[r] = rfl(xr.y);
    }

    float acc0[ROWS], acc1[ROWS];
    #pragma unroll
    for (int r = 0; r < ROWS; ++r) { acc0[r] = 0.0f; acc1[r] = 0.0f; }

    #pragma unroll 2            // keep rolled: full unroll caused scratch spills (R6)
    for (int h = 0; h < HID; ++h) {
        const float2 w0v = W0p[h * NCH + c];   // per-lane, coalesced 512B
        const float  bh  = b0p[h * NCH + c];
        const float2 w1v = W1p[h * NCH + c];

        #pragma unroll
        for (int r = 0; r < ROWS; ++r) {
            float pre = fmaf(sx0[r], w0v.x, fmaf(sx1[r], w0v.y, bh));
            float a   = __builtin_fabsf(pre);            // VOP3 abs modifier
            float t   = fmaf(A4, a, A3);
            t         = fmaf(t, a, A2);
            t         = fmaf(t, a, A1);
            float P   = fmaf(t, a, 1.0f);
            float P2  = P * P;
            float P4  = P2 * P2;
            float inv = __builtin_amdgcn_rcpf(P4);       // 1/P^4
            float q   = fmaf(-a, inv, pre + a);          // 2*gelu
            acc0[r]   = fmaf(q, w1v.x, acc0[r]);
            acc1[r]   = fmaf(q, w1v.y, acc1[r]);
        }
    }

    // Direct coalesced writeback: lanes consecutive in c -> 512B per row
    const float2 b1v = ((const float2*)b1)[c];
    float2* __restrict__ out2 = (float2*)out;
    #pragma unroll
    for (int r = 0; r < ROWS; ++r) {
        out2[(size_t)(rbase + r) * NCH + c] =
            make_float2(fmaf(0.5f, acc0[r], b1v.x), fmaf(0.5f, acc1[r], b1v.y));
    }
}

extern "C" void kernel_launch(void* const* d_in, const int* in_sizes, int n_in,
                              void* d_out, int out_size, void* d_ws, size_t ws_size,
                              hipStream_t stream) {
    const float* x  = (const float*)d_in[0];
    const float* W0 = (const float*)d_in[1];
    const float* b0 = (const float*)d_in[2];
    const float* W1 = (const float*)d_in[3];
    const float* b1 = (const float*)d_in[4];
    float* out = (float*)d_out;
    float* ws  = (float*)d_ws;   // needs 160 KB

    repack_kernel<<<dim3(HID * NCH * 2 / 256), dim3(256), 0, stream>>>(W0, b0, W1, ws);

    dim3 grid((BATCH / ROWS) * (NCH / TPB));   // 1024 * 4 = 4096
    mlp_main<<<grid, dim3(TPB), 0, stream>>>(x, ws, b1, out);
}

// Round 8
// 55.641 us; speedup vs baseline: 1.0986x; 1.0986x over previous
//
#include <hip/hip_runtime.h>

// 256 independent MLPs (2->32->2), 16384 rows. VALU-bound.
// Round 8 hybrid: lane=channel (per-lane VGPR weights, R6) + f32x2 row-pair
// packing (R5, halves regular-op stream). x row-pair vectors built ONCE
// (loop-invariant; R5 rebuilt splats per iter = its bloat). rcp shared 4-way
// (1 v_rcp + 9 muls per 4 evals). Direct coalesced 512B stores, no LDS.

typedef float f32x2 __attribute__((ext_vector_type(2)));

#define NCH   256
#define HID   32
#define BATCH 16384
#define TPB   256   // c = threadIdx.x; 4 waves/block
#define ROWS  16    // batch rows per block (and per thread)
#define NP    (ROWS / 2)   // 8 row-pairs

// d_ws layout (floats): W0p[HID][NCH][2] | b0p[HID][NCH] | W1p[HID][NCH][2]
#define W0P_OFF 0
#define B0P_OFF (HID * NCH * 2)
#define W1P_OFF (B0P_OFF + HID * NCH)

__global__ __launch_bounds__(256) void repack_kernel(
    const float* __restrict__ W0,   // [NCH][HID][2]
    const float* __restrict__ b0,   // [NCH][HID]
    const float* __restrict__ W1,   // [NCH][2][HID]
    float* __restrict__ ws)
{
    int t = blockIdx.x * blockDim.x + threadIdx.x;   // 16384 threads
    {   // W0p[(h*NCH + c)*2 + i] = W0[c*64 + h*2 + i]
        int i = t & 1, c = (t >> 1) & 255, h = t >> 9;
        ws[W0P_OFF + t] = W0[c * (HID * 2) + h * 2 + i];
    }
    if (t < HID * NCH) {   // b0p[h*NCH + c] = b0[c*32 + h]
        int c = t & 255, h = t >> 8;
        ws[B0P_OFF + t] = b0[c * HID + h];
    }
    {   // W1p[(h*NCH + c)*2 + o] = W1[c*64 + o*32 + h]
        int o = t & 1, c = (t >> 1) & 255, h = t >> 9;
        ws[W1P_OFF + t] = W1[c * (2 * HID) + o * HID + h];
    }
}

static __device__ __forceinline__ float rfl(float v) {
    return __uint_as_float(__builtin_amdgcn_readfirstlane(__float_as_uint(v)));
}
static __device__ __forceinline__ f32x2 vabs2(f32x2 v) {
    f32x2 r; r.x = __builtin_fabsf(v.x); r.y = __builtin_fabsf(v.y); return r;
}

__global__ __launch_bounds__(TPB, 4) void mlp_main(
    const float* __restrict__ x,    // [BATCH][2]
    const float* __restrict__ ws,   // repacked weights
    const float* __restrict__ b1,   // [NCH][2]
    float* __restrict__ out)        // [BATCH][NCH][2]
{
    // A&S 7.1.27 erf poly, sqrt(2) folded (|eps|<=5e-4); q = 2*gelu.
    const f32x2 A1 = {0.19685390f, 0.19685390f};
    const f32x2 A2 = {0.11519450f, 0.11519450f};
    const f32x2 A3 = {3.4365516e-4f, 3.4365516e-4f};
    const f32x2 A4 = {0.019527f, 0.019527f};
    const f32x2 ONE = {1.0f, 1.0f};

    const float2* __restrict__ W0p = (const float2*)(ws + W0P_OFF);  // [h*NCH+c] -> (wa,wb)
    const float*  __restrict__ b0p = ws + B0P_OFF;                   // [h*NCH+c]
    const float2* __restrict__ W1p = (const float2*)(ws + W1P_OFF);  // [h*NCH+c] -> (w1a,w1b)

    const int c     = threadIdx.x;           // lane+wave = channel
    const int rbase = blockIdx.x * ROWS;

    // Row-pair x vectors: wave-uniform scalars, built ONCE (loop-invariant).
    f32x2 px0[NP], px1[NP];
    const float2* __restrict__ x2 = (const float2*)x;
    #pragma unroll
    for (int p = 0; p < NP; ++p) {
        float2 xa = x2[rbase + 2 * p];
        float2 xb = x2[rbase + 2 * p + 1];
        px0[p] = f32x2{rfl(xa.x), rfl(xb.x)};
        px1[p] = f32x2{rfl(xa.y), rfl(xb.y)};
    }

    f32x2 acc0[NP], acc1[NP];
    #pragma unroll
    for (int p = 0; p < NP; ++p) { acc0[p] = f32x2{0,0}; acc1[p] = f32x2{0,0}; }

    #pragma unroll 2
    for (int h = 0; h < HID; ++h) {
        const float2 w0v = W0p[h * NCH + c];   // per-lane, coalesced
        const float  bh  = b0p[h * NCH + c];
        const float2 w1v = W1p[h * NCH + c];
        const f32x2 wav  = {w0v.x, w0v.x};     // broadcast pairs: <=5 movs/h,
        const f32x2 wbv  = {w0v.y, w0v.y};     // amortized over 16 evals
        const f32x2 bhv  = {bh, bh};
        const f32x2 w1av = {w1v.x, w1v.x};
        const f32x2 w1bv = {w1v.y, w1v.y};

        #pragma unroll
        for (int g = 0; g < NP / 2; ++g) {     // 4 quad-groups (2 pairs each)
            const int pA = 2 * g, pB = 2 * g + 1;
            f32x2 preA = px0[pA] * wav + (px1[pA] * wbv + bhv);
            f32x2 preB = px0[pB] * wav + (px1[pB] * wbv + bhv);
            f32x2 aA = vabs2(preA), aB = vabs2(preB);

            f32x2 tA = A4 * aA + A3; tA = tA * aA + A2; tA = tA * aA + A1;
            f32x2 PA = tA * aA + ONE;
            f32x2 tB = A4 * aB + A3; tB = tB * aB + A2; tB = tB * aB + A1;
            f32x2 PB = tB * aB + ONE;

            f32x2 P2A = PA * PA, P4A = P2A * P2A;
            f32x2 P2B = PB * PB, P4B = P2B * P2B;

            // 4-way shared reciprocal: 1 v_rcp + 9 muls for 4 inverses
            const float mA = P4A.x * P4A.y;
            const float mB = P4B.x * P4B.y;
            const float R  = __builtin_amdgcn_rcpf(mA * mB);
            const float RA = R * mB;           // = 1/(P4A.x*P4A.y)
            const float RB = R * mA;
            const f32x2 invA = {RA * P4A.y, RA * P4A.x};
            const f32x2 invB = {RB * P4B.y, RB * P4B.x};

            // q = 2*gelu = (pre + a) - a/P^4
            f32x2 qA = (preA + aA) - aA * invA;
            f32x2 qB = (preB + aB) - aB * invB;

            acc0[pA] = acc0[pA] + qA * w1av;
            acc1[pA] = acc1[pA] + qA * w1bv;
            acc0[pB] = acc0[pB] + qB * w1av;
            acc1[pB] = acc1[pB] + qB * w1bv;
        }
    }

    // Direct coalesced writeback: lanes consecutive in c -> 512B per row
    const float2 b1v = ((const float2*)b1)[c];
    float2* __restrict__ out2 = (float2*)out;
    #pragma unroll
    for (int p = 0; p < NP; ++p) {
        out2[(size_t)(rbase + 2 * p) * NCH + c] =
            make_float2(fmaf(0.5f, acc0[p].x, b1v.x), fmaf(0.5f, acc1[p].x, b1v.y));
        out2[(size_t)(rbase + 2 * p + 1) * NCH + c] =
            make_float2(fmaf(0.5f, acc0[p].y, b1v.x), fmaf(0.5f, acc1[p].y, b1v.y));
    }
}

extern "C" void kernel_launch(void* const* d_in, const int* in_sizes, int n_in,
                              void* d_out, int out_size, void* d_ws, size_t ws_size,
                              hipStream_t stream) {
    const float* x  = (const float*)d_in[0];
    const float* W0 = (const float*)d_in[1];
    const float* b0 = (const float*)d_in[2];
    const float* W1 = (const float*)d_in[3];
    const float* b1 = (const float*)d_in[4];
    float* out = (float*)d_out;
    float* ws  = (float*)d_ws;   // needs 160 KB

    repack_kernel<<<dim3(HID * NCH * 2 / 256), dim3(256), 0, stream>>>(W0, b0, W1, ws);

    dim3 grid(BATCH / ROWS);     // 1024 blocks x 256 threads
    mlp_main<<<grid, dim3(TPB), 0, stream>>>(x, ws, b1, out);
}

// Round 9
// 55.560 us; speedup vs baseline: 1.1002x; 1.0015x over previous
//
#include <hip/hip_runtime.h>

// 256 independent MLPs (2->32->2), 16384 rows. VALU-bound; issue ceiling ~66%
// (m07). Round 9: R8 structure but x row-pairs PRE-PACKED in ws and loaded as
// float4 vector loads -> all inner-loop operands are honest VGPRs. R8's VGPR=48
// showed SGPR-origin f32x2 (readfirstlane) gets rematerialized per use (VOP3P
// reads <=1 SGPR); VGPR-origin data cannot be remat'd -> packed math stays clean.

typedef float f32x2 __attribute__((ext_vector_type(2)));

#define NCH   256
#define HID   32
#define BATCH 16384
#define TPB   256   // c = threadIdx.x; 4 waves/block
#define ROWS  16    // batch rows per block/thread
#define NP    (ROWS / 2)   // 8 row-pairs

// ws (floats): W0p[HID][NCH][2] | b0p[HID][NCH] | W1p[HID][NCH][2] | XP[BATCH/2][4]
#define W0P_OFF 0
#define B0P_OFF (HID * NCH * 2)
#define W1P_OFF (B0P_OFF + HID * NCH)
#define XP_OFF  (W1P_OFF + HID * NCH * 2)   // +32768 floats = 128 KB

__global__ __launch_bounds__(256) void repack_kernel(
    const float* __restrict__ x,    // [BATCH][2]
    const float* __restrict__ W0,   // [NCH][HID][2]
    const float* __restrict__ b0,   // [NCH][HID]
    const float* __restrict__ W1,   // [NCH][2][HID]
    float* __restrict__ ws)
{
    int t = blockIdx.x * blockDim.x + threadIdx.x;   // 16384 threads
    {   // W0p[(h*NCH + c)*2 + i] = W0[c*64 + h*2 + i]
        int i = t & 1, c = (t >> 1) & 255, h = t >> 9;
        ws[W0P_OFF + t] = W0[c * (HID * 2) + h * 2 + i];
    }
    if (t < HID * NCH) {   // b0p[h*NCH + c] = b0[c*32 + h]
        int c = t & 255, h = t >> 8;
        ws[B0P_OFF + t] = b0[c * HID + h];
    }
    {   // W1p[(h*NCH + c)*2 + o] = W1[c*64 + o*32 + h]
        int o = t & 1, c = (t >> 1) & 255, h = t >> 9;
        ws[W1P_OFF + t] = W1[c * (2 * HID) + o * HID + h];
    }
    if (t < BATCH / 2) {   // XP[p] = {xA.x, xB.x, xA.y, xB.y} for rows 2p,2p+1
        const float2* x2 = (const float2*)x;
        float2 xa = x2[2 * t], xb = x2[2 * t + 1];
        float4 v = make_float4(xa.x, xb.x, xa.y, xb.y);
        ((float4*)(ws + XP_OFF))[t] = v;
    }
}

static __device__ __forceinline__ f32x2 vabs2(f32x2 v) {
    f32x2 r; r.x = __builtin_fabsf(v.x); r.y = __builtin_fabsf(v.y); return r;
}

__global__ __launch_bounds__(TPB, 4) void mlp_main(
    const float* __restrict__ ws,   // repacked weights + x pairs
    const float* __restrict__ b1,   // [NCH][2]
    float* __restrict__ out)        // [BATCH][NCH][2]
{
    // A&S 7.1.27 erf poly, sqrt(2) folded (|eps|<=5e-4); q = 2*gelu.
    const f32x2 A1 = {0.19685390f, 0.19685390f};
    const f32x2 A2 = {0.11519450f, 0.11519450f};
    const f32x2 A3 = {3.4365516e-4f, 3.4365516e-4f};
    const f32x2 A4 = {0.019527f, 0.019527f};
    const f32x2 ONE = {1.0f, 1.0f};

    const float2* __restrict__ W0p = (const float2*)(ws + W0P_OFF);
    const float*  __restrict__ b0p = ws + B0P_OFF;
    const float2* __restrict__ W1p = (const float2*)(ws + W1P_OFF);
    const float4* __restrict__ XP  = (const float4*)(ws + XP_OFF);

    const int c     = threadIdx.x;           // lane+wave = channel
    const int rbase = blockIdx.x * ROWS;
    const int pbase = blockIdx.x * NP;

    // x row-pairs: plain vector loads -> native VGPR pairs (no SGPR origin,
    // no remat). Wave-uniform address = broadcast, data per-lane identical.
    f32x2 px0[NP], px1[NP];
    #pragma unroll
    for (int p = 0; p < NP; ++p) {
        float4 v = XP[pbase + p];
        px0[p] = f32x2{v.x, v.y};
        px1[p] = f32x2{v.z, v.w};
    }

    f32x2 acc0[NP], acc1[NP];
    #pragma unroll
    for (int p = 0; p < NP; ++p) { acc0[p] = f32x2{0,0}; acc1[p] = f32x2{0,0}; }

    #pragma unroll 2
    for (int h = 0; h < HID; ++h) {
        const float2 w0v = W0p[h * NCH + c];   // per-lane, coalesced
        const float  bh  = b0p[h * NCH + c];
        const float2 w1v = W1p[h * NCH + c];
        const f32x2 wav  = {w0v.x, w0v.x};     // <=5 movs/h, amortized 16 evals
        const f32x2 wbv  = {w0v.y, w0v.y};
        const f32x2 bhv  = {bh, bh};
        const f32x2 w1av = {w1v.x, w1v.x};
        const f32x2 w1bv = {w1v.y, w1v.y};

        #pragma unroll
        for (int g = 0; g < NP / 2; ++g) {     // 4 quad-groups (2 pairs each)
            const int pA = 2 * g, pB = 2 * g + 1;
            f32x2 preA = px0[pA] * wav + (px1[pA] * wbv + bhv);
            f32x2 preB = px0[pB] * wav + (px1[pB] * wbv + bhv);
            f32x2 aA = vabs2(preA), aB = vabs2(preB);

            f32x2 tA = A4 * aA + A3; tA = tA * aA + A2; tA = tA * aA + A1;
            f32x2 PA = tA * aA + ONE;
            f32x2 tB = A4 * aB + A3; tB = tB * aB + A2; tB = tB * aB + A1;
            f32x2 PB = tB * aB + ONE;

            f32x2 P2A = PA * PA, P4A = P2A * P2A;
            f32x2 P2B = PB * PB, P4B = P2B * P2B;

            // 4-way shared reciprocal: 1 v_rcp + 9 muls for 4 inverses
            const float mA = P4A.x * P4A.y;
            const float mB = P4B.x * P4B.y;
            const float R  = __builtin_amdgcn_rcpf(mA * mB);
            const float RA = R * mB;
            const float RB = R * mA;
            const f32x2 invA = {RA * P4A.y, RA * P4A.x};
            const f32x2 invB = {RB * P4B.y, RB * P4B.x};

            // q = 2*gelu = (pre + a) - a/P^4
            f32x2 qA = (preA + aA) - aA * invA;
            f32x2 qB = (preB + aB) - aB * invB;

            acc0[pA] = acc0[pA] + qA * w1av;
            acc1[pA] = acc1[pA] + qA * w1bv;
            acc0[pB] = acc0[pB] + qB * w1av;
            acc1[pB] = acc1[pB] + qB * w1bv;
        }
    }

    // Direct coalesced writeback: lanes consecutive in c -> 512B per row
    const float2 b1v = ((const float2*)b1)[c];
    float2* __restrict__ out2 = (float2*)out;
    #pragma unroll
    for (int p = 0; p < NP; ++p) {
        out2[(size_t)(rbase + 2 * p) * NCH + c] =
            make_float2(fmaf(0.5f, acc0[p].x, b1v.x), fmaf(0.5f, acc1[p].x, b1v.y));
        out2[(size_t)(rbase + 2 * p + 1) * NCH + c] =
            make_float2(fmaf(0.5f, acc0[p].y, b1v.x), fmaf(0.5f, acc1[p].y, b1v.y));
    }
}

extern "C" void kernel_launch(void* const* d_in, const int* in_sizes, int n_in,
                              void* d_out, int out_size, void* d_ws, size_t ws_size,
                              hipStream_t stream) {
    const float* x  = (const float*)d_in[0];
    const float* W0 = (const float*)d_in[1];
    const float* b0 = (const float*)d_in[2];
    const float* W1 = (const float*)d_in[3];
    const float* b1 = (const float*)d_in[4];
    float* out = (float*)d_out;
    float* ws  = (float*)d_ws;   // needs 288 KB

    repack_kernel<<<dim3(HID * NCH * 2 / 256), dim3(256), 0, stream>>>(x, W0, b0, W1, ws);

    dim3 grid(BATCH / ROWS);     // 1024 blocks x 256 threads
    mlp_main<<<grid, dim3(TPB), 0, stream>>>(ws, b1, out);
}